// Round 10
// baseline (496.996 us; speedup 1.0000x reference)
//
#include <hip/hip_runtime.h>
#include <cstdint>
#include <cstddef>

typedef unsigned short u16;
typedef __attribute__((ext_vector_type(2))) unsigned short u16x2;
typedef __attribute__((ext_vector_type(4))) unsigned short u16x4;
typedef __attribute__((ext_vector_type(8))) unsigned short u16x8;
typedef __attribute__((ext_vector_type(4))) float f32x4;
typedef __attribute__((ext_vector_type(8))) __bf16 bf16x8;

#define B_    2
#define L_    2048
#define DIM_  2048
#define H_    16
#define HD_   128
#define NQKV_ 6144
#define M_    4096   // B_*L_

__device__ __forceinline__ float b2f(u16 h) {
  union { unsigned u; float f; } v; v.u = ((unsigned)h) << 16; return v.f;
}
__device__ __forceinline__ u16 f2bf(float f) {
  unsigned u = __float_as_uint(f);
  u += 0x7fffu + ((u >> 16) & 1u);   // RNE
  return (u16)(u >> 16);
}
__device__ __forceinline__ f32x4 mfma16(bf16x8 a, bf16x8 b, f32x4 c) {
  return __builtin_amdgcn_mfma_f32_16x16x32_bf16(a, b, c, 0, 0, 0);
}
__device__ __forceinline__ void async16(const void* g, void* l) {
  __builtin_amdgcn_global_load_lds(
      (const __attribute__((address_space(1))) unsigned*)g,
      (__attribute__((address_space(3))) unsigned*)l, 16, 0, 0);
}

// ---------------------------------------------------------------------------
// Pre-pass 1: straight f32 -> bf16 convert (x). 4 elems/thread.
// ---------------------------------------------------------------------------
__global__ __launch_bounds__(256) void cvt_bf16(
    const float* __restrict__ src, u16* __restrict__ dst) {
  int i = (blockIdx.x * 256 + threadIdx.x) * 4;
  f32x4 v = *(const f32x4*)&src[i];
  u16x4 o;
  #pragma unroll
  for (int j = 0; j < 4; ++j) o[j] = f2bf(v[j]);
  *(u16x4*)&dst[i] = o;
}

// ---------------------------------------------------------------------------
// Pre-pass 2: f32 (R x C) -> bf16 transposed (C x R). 64x64 LDS tile.
// ---------------------------------------------------------------------------
__global__ __launch_bounds__(256) void transpose_cvt(
    const float* __restrict__ src, u16* __restrict__ dst, int R, int C) {
  __shared__ u16 tile[64][66];
  int r0 = blockIdx.y * 64, c0 = blockIdx.x * 64;
  #pragma unroll
  for (int i = 0; i < 16; ++i) {
    int f = i * 256 + threadIdx.x;
    int r = f >> 6, c = f & 63;
    tile[r][c] = f2bf(src[(size_t)(r0 + r) * C + (c0 + c)]);
  }
  __syncthreads();
  #pragma unroll
  for (int i = 0; i < 8; ++i) {
    int f = i * 256 + threadIdx.x;
    int cr = f >> 5, rp = (f & 31) * 2;
    u16x2 v = {tile[rp][cr], tile[rp + 1][cr]};
    *(u16x2*)&dst[(size_t)(c0 + cr) * R + (r0 + rp)] = v;
  }
}

// ---------------------------------------------------------------------------
// m97-style GEMM: C[M,N] = A[M,K] * Bt[N,K]^T, all-bf16 inputs, pure
// async16 (global_load_lds dwordx4) staging. 128x128 tile, BK=32, 256 thr.
// MODE 1: scatter epilogue into Q/K/V (B*H,L,D) bf16 buffers. t/h/b are
//         block-uniform -> hoisted [round 8: ~15 us gain, kept].
//         Q and K heads are stored in INTERLEAVED-PAIR layout: position
//         2d holds x1(d), 2d+1 holds x2(d) (d = 0..63). QK^T is invariant
//         under any d-permutation applied consistently to Q and K; V keeps
//         the natural layout. This makes rotary pairs ADJACENT so rotary_k
//         can run fully vectorized (u16x8 per thread).
// MODE 2: bias(f32)-add epilogue, f32 row-major store
// ---------------------------------------------------------------------------
template <int MODE>
__global__ __launch_bounds__(256) void gemm_bt(
    const u16* __restrict__ A, const u16* __restrict__ Bt,
    u16* __restrict__ D0, u16* __restrict__ D1, u16* __restrict__ D2,
    const float* __restrict__ bias, float* __restrict__ outp,
    int M, int N, int K) {
  __shared__ __align__(16) u16 Alds[128 * 32];
  __shared__ __align__(16) u16 Blds[128 * 32];
  const int tid = threadIdx.x;
  const int wave = tid >> 6, lane = tid & 63;
  const int wm = wave >> 1, wn = wave & 1;
  const int ln = lane & 15, qd = lane >> 4;
  const int m0 = blockIdx.y * 128, n0 = blockIdx.x * 128;

  f32x4 acc[4][4];
  #pragma unroll
  for (int i = 0; i < 4; ++i)
    #pragma unroll
    for (int j = 0; j < 4; ++j) acc[i][j] = (f32x4){0.f, 0.f, 0.f, 0.f};

  for (int k0 = 0; k0 < K; k0 += 32) {
    __syncthreads();                     // prev iter's fragment ds_reads done
    #pragma unroll
    for (int j = 0; j < 2; ++j) {
      int f = (j * 256 + tid) * 8;       // flat elem in 128x32 tile
      int r = f >> 5, c = f & 31;
      async16(&A[(size_t)(m0 + r) * K + (k0 + c)], &Alds[j * 2048 + wave * 512]);
      async16(&Bt[(size_t)(n0 + r) * K + (k0 + c)], &Blds[j * 2048 + wave * 512]);
    }
    __syncthreads();                     // drains vmcnt before use
    bf16x8 af[4], bfr[4];
    #pragma unroll
    for (int mi = 0; mi < 4; ++mi)
      af[mi] = *(const bf16x8*)&Alds[(wm * 64 + mi * 16 + ln) * 32 + qd * 8];
    #pragma unroll
    for (int ni = 0; ni < 4; ++ni)
      bfr[ni] = *(const bf16x8*)&Blds[(wn * 64 + ni * 16 + ln) * 32 + qd * 8];
    #pragma unroll
    for (int mi = 0; mi < 4; ++mi)
      #pragma unroll
      for (int ni = 0; ni < 4; ++ni)
        acc[mi][ni] = mfma16(af[mi], bfr[ni], acc[mi][ni]);
  }

  // epilogue: C/D layout col=lane&15, row=quad*4+reg  [m89-verified]
  if (MODE == 2) {
    #pragma unroll
    for (int mi = 0; mi < 4; ++mi)
      #pragma unroll
      for (int ni = 0; ni < 4; ++ni)
        #pragma unroll
        for (int r = 0; r < 4; ++r) {
          int row = m0 + wm * 64 + mi * 16 + qd * 4 + r;
          int col = n0 + wn * 64 + ni * 16 + ln;
          outp[(size_t)row * N + col] = acc[mi][ni][r] + bias[col];
        }
  } else {
    const int t  = n0 >> 11;             // 0=q, 1=k, 2=v   (block-uniform)
    const int hh = (n0 & 2047) >> 7;     // head            (block-uniform)
    const int bb = m0 >> 11;             // batch           (block-uniform)
    const int l0 = (m0 & 2047) + wm * 64;
    // Q/K (t<2): interleaved-pair store pos = ((d&63)<<1)|(d>>6), where
    // d = wn*64 + ln + ni*16  ->  pos = ((ln+ni*16)<<1) | wn.
    // V (t==2): natural pos = wn*64 + ln + ni*16.
    const int d0    = (t != 2) ? (((ln) << 1) | wn) : (wn * 64 + ln);
    const int dstep = (t != 2) ? 32 : 16;
    u16* dst = (t == 0) ? D0 : ((t == 1) ? D1 : D2);
    u16* basep = dst + ((size_t)(bb * H_ + hh) * L_) * HD_;
    #pragma unroll
    for (int mi = 0; mi < 4; ++mi)
      #pragma unroll
      for (int r = 0; r < 4; ++r) {
        int l = l0 + mi * 16 + qd * 4 + r;
        #pragma unroll
        for (int ni = 0; ni < 4; ++ni)
          basep[(size_t)l * HD_ + d0 + ni * dstep] = f2bf(acc[mi][ni][r]);
      }
  }
}

// ---------------------------------------------------------------------------
// In-place rotary on Q and K in INTERLEAVED-PAIR layout (B*H, L, 128):
// position 2d = x1(d), 2d+1 = x2(d). Fully vectorized: each thread does
// 4 pairs = one u16x8 (16 B) load + f32x4 cos + f32x4 sin + one 16 B store.
// Block 256 thr = 2 tensors x 8 rows x 16 threads; grid = 65536/8 = 8192.
// Wave = 4 consecutive rows of one tensor -> 1 KiB contiguous per wave.
// ---------------------------------------------------------------------------
__global__ __launch_bounds__(256) void rotary_k(
    u16* __restrict__ Q, u16* __restrict__ Kb,
    const float* __restrict__ cs, const float* __restrict__ sn) {
  const int tid = threadIdx.x;
  const int tensor = tid >> 7;            // 0 = Q, 1 = K
  const int rsub = (tid >> 4) & 7;        // row within block's 8
  const int j = tid & 15;                 // 16 threads per row
  const int row = blockIdx.x * 8 + rsub;  // flat (bh*L + l)
  const int l = row & (L_ - 1);
  u16* P = tensor ? Kb : Q;
  size_t base = (size_t)row * HD_ + j * 8;
  u16x8 v = *(const u16x8*)&P[base];
  f32x4 c = *(const f32x4*)&cs[l * 64 + j * 4];
  f32x4 s = *(const f32x4*)&sn[l * 64 + j * 4];
  u16x8 o;
  #pragma unroll
  for (int e = 0; e < 4; ++e) {
    float x1 = b2f(v[2 * e]), x2 = b2f(v[2 * e + 1]);
    o[2 * e]     = f2bf(x1 * c[e] - x2 * s[e]);
    o[2 * e + 1] = f2bf(x2 * c[e] + x1 * s[e]);
  }
  *(u16x8*)&P[base] = o;
}

// ---------------------------------------------------------------------------
// Flash attention. grid (16 qtiles, 32 bh), 256 thr (4 waves).
// Q,K,V all (B*H, L, 128) bf16. BM=128, BN=64 keys/iter.
// Q/K arrive in interleaved-pair d-layout (consistent for both operands ->
// QK^T invariant; V natural -> PV output unchanged). Kernel is BYTE-
// IDENTICAL to round 9 (proven 170-172 us, 116 VGPR, 21% occupancy).
//
// Session rules (learned rounds 4-8):
//  - VGPR <= 128 or occupancy halves (64-granular quantum).
//  - NO sched_barrier/inline-asm fences here (pin live ranges, +24 VGPR).
//  - NO defer-max branch (+24 VGPR).
//  - Occupancy (3 blocks/CU) is the latency hider.
//
// LDS swizzles (both-sides, rule #21):
//   K/Q tiles: elem = row*128 + (col ^ ((row&7)<<3)); staged via inverse-
//     swizzled GLOBAL source (global_load_lds writes LDS linearly).
//   Vlds [128][64]: elem = row*64 + (col ^ (((row>>1)&7)<<3)).
//   Plds stride-72. LDS = 50 KB -> 3 blocks/CU.
// Deferred l-reduce: lsum kept PER-LANE, quad-reduced once in epilogue.
// ---------------------------------------------------------------------------
__global__ __launch_bounds__(256, 4) void attn_k(
    const u16* __restrict__ Q, const u16* __restrict__ Kb,
    const u16* __restrict__ V, u16* __restrict__ Ao) {
  __shared__ __align__(16) u16 lds[25600];     // 50 KB
  u16* Klds = lds;               // [64 keys][128 d]  (swizzled)
  u16* Vlds = lds + 8192;        // [128 d][64 keys]  (swizzled)
  u16* Plds = lds + 16384;       // [128 q][72], keys 0..63 used
  const int tid = threadIdx.x;
  const int w = tid >> 6, lane = tid & 63;
  const int ln = lane & 15, qd = lane >> 4;
  const int qt = blockIdx.x, bh = blockIdx.y;
  const int b = bh >> 4, h = bh & 15;
  const size_t slab = (size_t)bh * (L_ * HD_);
  const int vd0 = 2 * lane;                    // V staging: d-pair

  // stage Q tile (contiguous 32 KB, overlays K+V) via async16, pre-swizzled
  #pragma unroll
  for (int j = 0; j < 8; ++j) {
    int oe = j * 2048 + w * 512 + lane * 8;        // linear LDS elem offset
    int se = oe ^ (((oe >> 7) & 7) << 3);          // swizzled global source
    async16(&Q[slab + (size_t)qt * 16384 + se], &lds[j * 2048 + w * 512]);
  }
  __syncthreads();
  bf16x8 aq[2][4];                         // Q fragments in registers
  #pragma unroll
  for (int mi = 0; mi < 2; ++mi) {
    int qrow = w * 32 + mi * 16 + ln;
    #pragma unroll
    for (int kc = 0; kc < 4; ++kc)
      aq[mi][kc] = *(const bf16x8*)&lds[qrow * 128 +
                                        ((kc * 32 + qd * 8) ^ ((qrow & 7) << 3))];
  }

  f32x4 o[2][8];
  #pragma unroll
  for (int i = 0; i < 2; ++i)
    #pragma unroll
    for (int j = 0; j < 8; ++j) o[i][j] = (f32x4){0.f, 0.f, 0.f, 0.f};
  float mst[2][4], lsum[2][4];             // lsum = PER-LANE partial sum
  #pragma unroll
  for (int i = 0; i < 2; ++i)
    #pragma unroll
    for (int r = 0; r < 4; ++r) { mst[i][r] = -1e30f; lsum[i][r] = 0.f; }
  const float SC = 0.12751744f;            // (1/sqrt(128)) * log2(e)

  for (int it = 0; it < 32; ++it) {
    // V global loads -> regs (no LDS touch; before barrier for latency)
    unsigned vv[2][8];
    #pragma unroll
    for (int n2 = 0; n2 < 2; ++n2) {
      int key0 = (w + n2 * 4) * 8;
      #pragma unroll
      for (int e = 0; e < 8; ++e)
        vv[n2][e] = *(const unsigned*)&V[slab + (size_t)(it * 64 + key0 + e) * 128 + vd0];
    }
    __syncthreads();                       // B1: prev iter's LDS readers done
    // K tile via async16, source pre-swizzled (see header comment)
    #pragma unroll
    for (int j = 0; j < 4; ++j) {
      int oe = j * 2048 + w * 512 + lane * 8;
      int se = oe ^ (((oe >> 7) & 7) << 3);
      async16(&Kb[slab + (size_t)it * 8192 + se], &Klds[j * 2048 + w * 512]);
    }
    // V transpose stores (swizzled [128][64]; conflict-free, see header)
    {
      int swz = (lane & 7) << 3;           // ((vd0>>1)&7)<<3, vd0 even
      #pragma unroll
      for (int n2 = 0; n2 < 2; ++n2) {
        int key0 = (w + n2 * 4) * 8;
        u16x8 lo, hi;
        #pragma unroll
        for (int e = 0; e < 8; ++e) {
          lo[e] = (u16)(vv[n2][e] & 0xffffu);
          hi[e] = (u16)(vv[n2][e] >> 16);
        }
        *(u16x8*)&Vlds[vd0 * 64 + (key0 ^ swz)] = lo;
        *(u16x8*)&Vlds[(vd0 + 1) * 64 + (key0 ^ swz)] = hi;
      }
    }
    __syncthreads();                       // B2: drains vmcnt (K) + lgkm (V)

    // S = Q K^T  (raw dot products; scale folded into softmax)
    f32x4 sa[2][4];
    #pragma unroll
    for (int i = 0; i < 2; ++i)
      #pragma unroll
      for (int j = 0; j < 4; ++j) sa[i][j] = (f32x4){0.f, 0.f, 0.f, 0.f};
    #pragma unroll
    for (int kc = 0; kc < 4; ++kc) {
      bf16x8 bk[4];
      #pragma unroll
      for (int ni = 0; ni < 4; ++ni) {
        int krow = ni * 16 + ln;
        bk[ni] = *(const bf16x8*)&Klds[krow * 128 +
                                       ((kc * 32 + qd * 8) ^ ((krow & 7) << 3))];
      }
      #pragma unroll
      for (int mi = 0; mi < 2; ++mi)
        #pragma unroll
        for (int ni = 0; ni < 4; ++ni)
          sa[mi][ni] = mfma16(aq[mi][kc], bk[ni], sa[mi][ni]);
    }

    // online softmax per q-row; row r of tile lives on one quad (16 lanes)
    #pragma unroll
    for (int mi = 0; mi < 2; ++mi) {
      #pragma unroll
      for (int r = 0; r < 4; ++r) {
        float tmax = -1e30f;
        #pragma unroll
        for (int ni = 0; ni < 4; ++ni) tmax = fmaxf(tmax, sa[mi][ni][r]);
        tmax *= SC;
        tmax = fmaxf(tmax, __shfl_xor(tmax, 1));
        tmax = fmaxf(tmax, __shfl_xor(tmax, 2));
        tmax = fmaxf(tmax, __shfl_xor(tmax, 4));
        tmax = fmaxf(tmax, __shfl_xor(tmax, 8));
        float mnew = fmaxf(mst[mi][r], tmax);
        float alpha = exp2f(mst[mi][r] - mnew);
        float p[4], rs = 0.f;
        #pragma unroll
        for (int ni = 0; ni < 4; ++ni) {
          p[ni] = exp2f(sa[mi][ni][r] * SC - mnew);
          rs += p[ni];
        }
        lsum[mi][r] = lsum[mi][r] * alpha + rs;  // per-lane partial
        mst[mi][r] = mnew;
        #pragma unroll
        for (int di = 0; di < 8; ++di) o[mi][di][r] *= alpha;
        #pragma unroll
        for (int ni = 0; ni < 4; ++ni)     // P in A-operand layout [q][key]
          Plds[(w * 32 + mi * 16 + qd * 4 + r) * 72 + ni * 16 + ln] = f2bf(p[ni]);
      }
    }

    __syncthreads();                       // B3: P writes visible

    // O += P V
    #pragma unroll
    for (int kc = 0; kc < 2; ++kc) {
      bf16x8 ap[2];
      #pragma unroll
      for (int mi = 0; mi < 2; ++mi)
        ap[mi] = *(const bf16x8*)&Plds[(w * 32 + mi * 16 + ln) * 72 + kc * 32 + qd * 8];
      #pragma unroll
      for (int di = 0; di < 8; ++di) {
        int vrow = di * 16 + ln;
        bf16x8 bv = *(const bf16x8*)&Vlds[vrow * 64 +
                         ((kc * 32 + qd * 8) ^ (((vrow >> 1) & 7) << 3))];
        o[0][di] = mfma16(ap[0], bv, o[0][di]);
        o[1][di] = mfma16(ap[1], bv, o[1][di]);
      }
    }
  }

  // epilogue: reduce per-lane lsum across the quad, normalize, write out
  #pragma unroll
  for (int mi = 0; mi < 2; ++mi) {
    #pragma unroll
    for (int r = 0; r < 4; ++r) {
      float l = lsum[mi][r];
      l += __shfl_xor(l, 1);
      l += __shfl_xor(l, 2);
      l += __shfl_xor(l, 4);
      l += __shfl_xor(l, 8);
      float inv = 1.0f / l;
      int lrow = qt * 128 + w * 32 + mi * 16 + qd * 4 + r;
      size_t orow = ((size_t)b * L_ + lrow) * DIM_ + (size_t)h * HD_;
      #pragma unroll
      for (int di = 0; di < 8; ++di)
        Ao[orow + di * 16 + ln] = f2bf(o[mi][di][r] * inv);
    }
  }
}

// ---------------------------------------------------------------------------
extern "C" void kernel_launch(void* const* d_in, const int* in_sizes, int n_in,
                              void* d_out, int out_size, void* d_ws, size_t ws_size,
                              hipStream_t stream) {
  const float* x    = (const float*)d_in[0];
  const float* cs   = (const float*)d_in[1];
  const float* sn   = (const float*)d_in[2];
  const float* wqkv = (const float*)d_in[3];
  const float* wout = (const float*)d_in[4];
  const float* bias = (const float*)d_in[5];
  u16* ws = (u16*)d_ws;

  // Workspace (u16 elems), 92.3 MB total with two time-multiplexed overlaps:
  //   wqkvT 12,582,912  (N=6144 x K=2048 bf16; REUSED for woutT after gemm1)
  //   xbfAo  8,388,608  (x_bf during gemm1; Ao after attn)
  //   Qb/Kbuf/Vbuf 3 x 8,388,608
  u16* wqkvT = ws;
  u16* woutT = ws;                        // same region, written after gemm1
  u16* xbfAo = wqkvT + 12582912;
  u16* Qb    = xbfAo + 8388608;
  u16* Kbuf  = Qb + 8388608;
  u16* Vbuf  = Kbuf + 8388608;

  cvt_bf16<<<dim3(8192), 256, 0, stream>>>(x, xbfAo);
  transpose_cvt<<<dim3(96, 32), 256, 0, stream>>>(wqkv, wqkvT, 2048, 6144);
  gemm_bt<1><<<dim3(48, 32), 256, 0, stream>>>(
      xbfAo, wqkvT, Qb, Kbuf, Vbuf, nullptr, nullptr, M_, NQKV_, DIM_);
  transpose_cvt<<<dim3(32, 32), 256, 0, stream>>>(wout, woutT, 2048, 2048);
  rotary_k<<<dim3(8192), 256, 0, stream>>>(Qb, Kbuf, cs, sn);
  attn_k<<<dim3(16, 32), 256, 0, stream>>>(Qb, Kbuf, Vbuf, xbfAo);
  gemm_bt<2><<<dim3(16, 32), 256, 0, stream>>>(
      xbfAo, woutT, nullptr, nullptr, nullptr, bias, (float*)d_out, M_, DIM_, DIM_);
}

// Round 11
// 493.832 us; speedup vs baseline: 1.0064x; 1.0064x over previous
//
#include <hip/hip_runtime.h>
#include <cstdint>
#include <cstddef>

typedef unsigned short u16;
typedef __attribute__((ext_vector_type(2))) unsigned short u16x2;
typedef __attribute__((ext_vector_type(4))) unsigned short u16x4;
typedef __attribute__((ext_vector_type(8))) unsigned short u16x8;
typedef __attribute__((ext_vector_type(4))) float f32x4;
typedef __attribute__((ext_vector_type(8))) __bf16 bf16x8;

#define B_    2
#define L_    2048
#define DIM_  2048
#define H_    16
#define HD_   128
#define NQKV_ 6144
#define M_    4096   // B_*L_

__device__ __forceinline__ float b2f(u16 h) {
  union { unsigned u; float f; } v; v.u = ((unsigned)h) << 16; return v.f;
}
__device__ __forceinline__ u16 f2bf(float f) {
  unsigned u = __float_as_uint(f);
  u += 0x7fffu + ((u >> 16) & 1u);   // RNE
  return (u16)(u >> 16);
}
__device__ __forceinline__ f32x4 mfma16(bf16x8 a, bf16x8 b, f32x4 c) {
  return __builtin_amdgcn_mfma_f32_16x16x32_bf16(a, b, c, 0, 0, 0);
}
__device__ __forceinline__ void async16(const void* g, void* l) {
  __builtin_amdgcn_global_load_lds(
      (const __attribute__((address_space(1))) unsigned*)g,
      (__attribute__((address_space(3))) unsigned*)l, 16, 0, 0);
}

// ---------------------------------------------------------------------------
// Pre-pass 1: straight f32 -> bf16 convert (x). 4 elems/thread.
// ---------------------------------------------------------------------------
__global__ __launch_bounds__(256) void cvt_bf16(
    const float* __restrict__ src, u16* __restrict__ dst) {
  int i = (blockIdx.x * 256 + threadIdx.x) * 4;
  f32x4 v = *(const f32x4*)&src[i];
  u16x4 o;
  #pragma unroll
  for (int j = 0; j < 4; ++j) o[j] = f2bf(v[j]);
  *(u16x4*)&dst[i] = o;
}

// ---------------------------------------------------------------------------
// Pre-pass 2: f32 (R x C) -> bf16 transposed (C x R). 64x64 LDS tile.
// ---------------------------------------------------------------------------
__global__ __launch_bounds__(256) void transpose_cvt(
    const float* __restrict__ src, u16* __restrict__ dst, int R, int C) {
  __shared__ u16 tile[64][66];
  int r0 = blockIdx.y * 64, c0 = blockIdx.x * 64;
  #pragma unroll
  for (int i = 0; i < 16; ++i) {
    int f = i * 256 + threadIdx.x;
    int r = f >> 6, c = f & 63;
    tile[r][c] = f2bf(src[(size_t)(r0 + r) * C + (c0 + c)]);
  }
  __syncthreads();
  #pragma unroll
  for (int i = 0; i < 8; ++i) {
    int f = i * 256 + threadIdx.x;
    int cr = f >> 5, rp = (f & 31) * 2;
    u16x2 v = {tile[rp][cr], tile[rp + 1][cr]};
    *(u16x2*)&dst[(size_t)(c0 + cr) * R + (r0 + rp)] = v;
  }
}

// ---------------------------------------------------------------------------
// m97-style GEMM: C[M,N] = A[M,K] * Bt[N,K]^T, all-bf16 inputs, pure
// async16 (global_load_lds dwordx4) staging. 128x128 tile, BK=32, 256 thr.
// MODE 1: scatter epilogue into Q/K/V (B*H,L,D) bf16 buffers. t/h/b are
//         block-uniform -> hoisted [round 8: ~15 us gain, kept].
//         Q and K heads are stored in INTERLEAVED-PAIR layout: position
//         2d holds x1(d), 2d+1 holds x2(d) (d = 0..63). QK^T is invariant
//         under any d-permutation applied consistently to Q and K; V keeps
//         the natural layout. This makes rotary pairs ADJACENT so rotary_k
//         can run fully vectorized (u16x8 per thread).
// MODE 2: bias(f32)-add epilogue, f32 row-major store
// ---------------------------------------------------------------------------
template <int MODE>
__global__ __launch_bounds__(256) void gemm_bt(
    const u16* __restrict__ A, const u16* __restrict__ Bt,
    u16* __restrict__ D0, u16* __restrict__ D1, u16* __restrict__ D2,
    const float* __restrict__ bias, float* __restrict__ outp,
    int M, int N, int K) {
  __shared__ __align__(16) u16 Alds[128 * 32];
  __shared__ __align__(16) u16 Blds[128 * 32];
  const int tid = threadIdx.x;
  const int wave = tid >> 6, lane = tid & 63;
  const int wm = wave >> 1, wn = wave & 1;
  const int ln = lane & 15, qd = lane >> 4;
  const int m0 = blockIdx.y * 128, n0 = blockIdx.x * 128;

  f32x4 acc[4][4];
  #pragma unroll
  for (int i = 0; i < 4; ++i)
    #pragma unroll
    for (int j = 0; j < 4; ++j) acc[i][j] = (f32x4){0.f, 0.f, 0.f, 0.f};

  for (int k0 = 0; k0 < K; k0 += 32) {
    __syncthreads();                     // prev iter's fragment ds_reads done
    #pragma unroll
    for (int j = 0; j < 2; ++j) {
      int f = (j * 256 + tid) * 8;       // flat elem in 128x32 tile
      int r = f >> 5, c = f & 31;
      async16(&A[(size_t)(m0 + r) * K + (k0 + c)], &Alds[j * 2048 + wave * 512]);
      async16(&Bt[(size_t)(n0 + r) * K + (k0 + c)], &Blds[j * 2048 + wave * 512]);
    }
    __syncthreads();                     // drains vmcnt before use
    bf16x8 af[4], bfr[4];
    #pragma unroll
    for (int mi = 0; mi < 4; ++mi)
      af[mi] = *(const bf16x8*)&Alds[(wm * 64 + mi * 16 + ln) * 32 + qd * 8];
    #pragma unroll
    for (int ni = 0; ni < 4; ++ni)
      bfr[ni] = *(const bf16x8*)&Blds[(wn * 64 + ni * 16 + ln) * 32 + qd * 8];
    #pragma unroll
    for (int mi = 0; mi < 4; ++mi)
      #pragma unroll
      for (int ni = 0; ni < 4; ++ni)
        acc[mi][ni] = mfma16(af[mi], bfr[ni], acc[mi][ni]);
  }

  // epilogue: C/D layout col=lane&15, row=quad*4+reg  [m89-verified]
  if (MODE == 2) {
    #pragma unroll
    for (int mi = 0; mi < 4; ++mi)
      #pragma unroll
      for (int ni = 0; ni < 4; ++ni)
        #pragma unroll
        for (int r = 0; r < 4; ++r) {
          int row = m0 + wm * 64 + mi * 16 + qd * 4 + r;
          int col = n0 + wn * 64 + ni * 16 + ln;
          outp[(size_t)row * N + col] = acc[mi][ni][r] + bias[col];
        }
  } else {
    const int t  = n0 >> 11;             // 0=q, 1=k, 2=v   (block-uniform)
    const int hh = (n0 & 2047) >> 7;     // head            (block-uniform)
    const int bb = m0 >> 11;             // batch           (block-uniform)
    const int l0 = (m0 & 2047) + wm * 64;
    // Q/K (t<2): interleaved-pair store pos = ((d&63)<<1)|(d>>6), where
    // d = wn*64 + ln + ni*16  ->  pos = ((ln+ni*16)<<1) | wn.
    // V (t==2): natural pos = wn*64 + ln + ni*16.
    const int d0    = (t != 2) ? (((ln) << 1) | wn) : (wn * 64 + ln);
    const int dstep = (t != 2) ? 32 : 16;
    u16* dst = (t == 0) ? D0 : ((t == 1) ? D1 : D2);
    u16* basep = dst + ((size_t)(bb * H_ + hh) * L_) * HD_;
    #pragma unroll
    for (int mi = 0; mi < 4; ++mi)
      #pragma unroll
      for (int r = 0; r < 4; ++r) {
        int l = l0 + mi * 16 + qd * 4 + r;
        #pragma unroll
        for (int ni = 0; ni < 4; ++ni)
          basep[(size_t)l * HD_ + d0 + ni * dstep] = f2bf(acc[mi][ni][r]);
      }
  }
}

// ---------------------------------------------------------------------------
// In-place rotary on Q and K in INTERLEAVED-PAIR layout (B*H, L, 128):
// position 2d = x1(d), 2d+1 = x2(d). Fully vectorized: each thread does
// 4 pairs = one u16x8 (16 B) load + f32x4 cos + f32x4 sin + one 16 B store.
// Block 256 thr = 2 tensors x 8 rows x 16 threads; grid = 65536/8 = 8192.
// ---------------------------------------------------------------------------
__global__ __launch_bounds__(256) void rotary_k(
    u16* __restrict__ Q, u16* __restrict__ Kb,
    const float* __restrict__ cs, const float* __restrict__ sn) {
  const int tid = threadIdx.x;
  const int tensor = tid >> 7;            // 0 = Q, 1 = K
  const int rsub = (tid >> 4) & 7;        // row within block's 8
  const int j = tid & 15;                 // 16 threads per row
  const int row = blockIdx.x * 8 + rsub;  // flat (bh*L + l)
  const int l = row & (L_ - 1);
  u16* P = tensor ? Kb : Q;
  size_t base = (size_t)row * HD_ + j * 8;
  u16x8 v = *(const u16x8*)&P[base];
  f32x4 c = *(const f32x4*)&cs[l * 64 + j * 4];
  f32x4 s = *(const f32x4*)&sn[l * 64 + j * 4];
  u16x8 o;
  #pragma unroll
  for (int e = 0; e < 4; ++e) {
    float x1 = b2f(v[2 * e]), x2 = b2f(v[2 * e + 1]);
    o[2 * e]     = f2bf(x1 * c[e] - x2 * s[e]);
    o[2 * e + 1] = f2bf(x2 * c[e] + x1 * s[e]);
  }
  *(u16x8*)&P[base] = o;
}

// ---------------------------------------------------------------------------
// Flash attention. grid = 512 flat blocks, 256 thr (4 waves).
// Q,K,V all (B*H, L, 128) bf16. BM=128, BN=64 keys/iter.
//
// XCD-AWARE BLOCK MAPPING (T1): with the old (16,32) grid, flat id =
// bh*16+qt and round-robin XCD assignment gives xcd = qt%8 -> every XCD
// hosts all 32 bh slabs (64 MB K/V working set vs 4 MB L2) -> the 16-way
// K/V reuse across qtiles is destroyed (FETCH 139 MB vs ~48 MB compulsory).
// New mapping: flat -> xcd = flat&7, li = flat>>3, bh = xcd*4 + (li>>4),
// qt = li&15 (bijective, 512 = 8*64). Under round-robin dispatch, XCD k
// serves bh in [4k,4k+4): all 16 qtiles of a bh stream the same K/V tiles
// through ONE L2 in near-lockstep -> fetch once, 15/16 L2 hits.
// Perf heuristic only: any dispatch order still computes correctly.
//
// Kernel body otherwise BYTE-IDENTICAL to round 9/10 (proven 169-172 us,
// 116 VGPR, 21% occupancy). Session rules (rounds 4-8):
//  - VGPR <= 128 or occupancy halves (64-granular quantum).
//  - NO sched_barrier/inline-asm fences here (pin live ranges, +24 VGPR).
//  - NO defer-max branch (+24 VGPR).
//  - Occupancy (3 blocks/CU) is the latency hider.
//
// LDS swizzles (both-sides, rule #21):
//   K/Q tiles: elem = row*128 + (col ^ ((row&7)<<3)); staged via inverse-
//     swizzled GLOBAL source (global_load_lds writes LDS linearly).
//   Vlds [128][64]: elem = row*64 + (col ^ (((row>>1)&7)<<3)).
//   Plds stride-72. LDS = 50 KB -> 3 blocks/CU.
// Deferred l-reduce: lsum kept PER-LANE, quad-reduced once in epilogue.
// ---------------------------------------------------------------------------
__global__ __launch_bounds__(256, 4) void attn_k(
    const u16* __restrict__ Q, const u16* __restrict__ Kb,
    const u16* __restrict__ V, u16* __restrict__ Ao) {
  __shared__ __align__(16) u16 lds[25600];     // 50 KB
  u16* Klds = lds;               // [64 keys][128 d]  (swizzled)
  u16* Vlds = lds + 8192;        // [128 d][64 keys]  (swizzled)
  u16* Plds = lds + 16384;       // [128 q][72], keys 0..63 used
  const int tid = threadIdx.x;
  const int w = tid >> 6, lane = tid & 63;
  const int ln = lane & 15, qd = lane >> 4;
  const int flat = blockIdx.x;                 // XCD-aware remap (see header)
  const int li = flat >> 3;
  const int bh = (flat & 7) * 4 + (li >> 4);
  const int qt = li & 15;
  const int b = bh >> 4, h = bh & 15;
  const size_t slab = (size_t)bh * (L_ * HD_);
  const int vd0 = 2 * lane;                    // V staging: d-pair

  // stage Q tile (contiguous 32 KB, overlays K+V) via async16, pre-swizzled
  #pragma unroll
  for (int j = 0; j < 8; ++j) {
    int oe = j * 2048 + w * 512 + lane * 8;        // linear LDS elem offset
    int se = oe ^ (((oe >> 7) & 7) << 3);          // swizzled global source
    async16(&Q[slab + (size_t)qt * 16384 + se], &lds[j * 2048 + w * 512]);
  }
  __syncthreads();
  bf16x8 aq[2][4];                         // Q fragments in registers
  #pragma unroll
  for (int mi = 0; mi < 2; ++mi) {
    int qrow = w * 32 + mi * 16 + ln;
    #pragma unroll
    for (int kc = 0; kc < 4; ++kc)
      aq[mi][kc] = *(const bf16x8*)&lds[qrow * 128 +
                                        ((kc * 32 + qd * 8) ^ ((qrow & 7) << 3))];
  }

  f32x4 o[2][8];
  #pragma unroll
  for (int i = 0; i < 2; ++i)
    #pragma unroll
    for (int j = 0; j < 8; ++j) o[i][j] = (f32x4){0.f, 0.f, 0.f, 0.f};
  float mst[2][4], lsum[2][4];             // lsum = PER-LANE partial sum
  #pragma unroll
  for (int i = 0; i < 2; ++i)
    #pragma unroll
    for (int r = 0; r < 4; ++r) { mst[i][r] = -1e30f; lsum[i][r] = 0.f; }
  const float SC = 0.12751744f;            // (1/sqrt(128)) * log2(e)

  for (int it = 0; it < 32; ++it) {
    // V global loads -> regs (no LDS touch; before barrier for latency)
    unsigned vv[2][8];
    #pragma unroll
    for (int n2 = 0; n2 < 2; ++n2) {
      int key0 = (w + n2 * 4) * 8;
      #pragma unroll
      for (int e = 0; e < 8; ++e)
        vv[n2][e] = *(const unsigned*)&V[slab + (size_t)(it * 64 + key0 + e) * 128 + vd0];
    }
    __syncthreads();                       // B1: prev iter's LDS readers done
    // K tile via async16, source pre-swizzled (see header comment)
    #pragma unroll
    for (int j = 0; j < 4; ++j) {
      int oe = j * 2048 + w * 512 + lane * 8;
      int se = oe ^ (((oe >> 7) & 7) << 3);
      async16(&Kb[slab + (size_t)it * 8192 + se], &Klds[j * 2048 + w * 512]);
    }
    // V transpose stores (swizzled [128][64]; conflict-free, see header)
    {
      int swz = (lane & 7) << 3;           // ((vd0>>1)&7)<<3, vd0 even
      #pragma unroll
      for (int n2 = 0; n2 < 2; ++n2) {
        int key0 = (w + n2 * 4) * 8;
        u16x8 lo, hi;
        #pragma unroll
        for (int e = 0; e < 8; ++e) {
          lo[e] = (u16)(vv[n2][e] & 0xffffu);
          hi[e] = (u16)(vv[n2][e] >> 16);
        }
        *(u16x8*)&Vlds[vd0 * 64 + (key0 ^ swz)] = lo;
        *(u16x8*)&Vlds[(vd0 + 1) * 64 + (key0 ^ swz)] = hi;
      }
    }
    __syncthreads();                       // B2: drains vmcnt (K) + lgkm (V)

    // S = Q K^T  (raw dot products; scale folded into softmax)
    f32x4 sa[2][4];
    #pragma unroll
    for (int i = 0; i < 2; ++i)
      #pragma unroll
      for (int j = 0; j < 4; ++j) sa[i][j] = (f32x4){0.f, 0.f, 0.f, 0.f};
    #pragma unroll
    for (int kc = 0; kc < 4; ++kc) {
      bf16x8 bk[4];
      #pragma unroll
      for (int ni = 0; ni < 4; ++ni) {
        int krow = ni * 16 + ln;
        bk[ni] = *(const bf16x8*)&Klds[krow * 128 +
                                       ((kc * 32 + qd * 8) ^ ((krow & 7) << 3))];
      }
      #pragma unroll
      for (int mi = 0; mi < 2; ++mi)
        #pragma unroll
        for (int ni = 0; ni < 4; ++ni)
          sa[mi][ni] = mfma16(aq[mi][kc], bk[ni], sa[mi][ni]);
    }

    // online softmax per q-row; row r of tile lives on one quad (16 lanes)
    #pragma unroll
    for (int mi = 0; mi < 2; ++mi) {
      #pragma unroll
      for (int r = 0; r < 4; ++r) {
        float tmax = -1e30f;
        #pragma unroll
        for (int ni = 0; ni < 4; ++ni) tmax = fmaxf(tmax, sa[mi][ni][r]);
        tmax *= SC;
        tmax = fmaxf(tmax, __shfl_xor(tmax, 1));
        tmax = fmaxf(tmax, __shfl_xor(tmax, 2));
        tmax = fmaxf(tmax, __shfl_xor(tmax, 4));
        tmax = fmaxf(tmax, __shfl_xor(tmax, 8));
        float mnew = fmaxf(mst[mi][r], tmax);
        float alpha = exp2f(mst[mi][r] - mnew);
        float p[4], rs = 0.f;
        #pragma unroll
        for (int ni = 0; ni < 4; ++ni) {
          p[ni] = exp2f(sa[mi][ni][r] * SC - mnew);
          rs += p[ni];
        }
        lsum[mi][r] = lsum[mi][r] * alpha + rs;  // per-lane partial
        mst[mi][r] = mnew;
        #pragma unroll
        for (int di = 0; di < 8; ++di) o[mi][di][r] *= alpha;
        #pragma unroll
        for (int ni = 0; ni < 4; ++ni)     // P in A-operand layout [q][key]
          Plds[(w * 32 + mi * 16 + qd * 4 + r) * 72 + ni * 16 + ln] = f2bf(p[ni]);
      }
    }

    __syncthreads();                       // B3: P writes visible

    // O += P V
    #pragma unroll
    for (int kc = 0; kc < 2; ++kc) {
      bf16x8 ap[2];
      #pragma unroll
      for (int mi = 0; mi < 2; ++mi)
        ap[mi] = *(const bf16x8*)&Plds[(w * 32 + mi * 16 + ln) * 72 + kc * 32 + qd * 8];
      #pragma unroll
      for (int di = 0; di < 8; ++di) {
        int vrow = di * 16 + ln;
        bf16x8 bv = *(const bf16x8*)&Vlds[vrow * 64 +
                         ((kc * 32 + qd * 8) ^ (((vrow >> 1) & 7) << 3))];
        o[0][di] = mfma16(ap[0], bv, o[0][di]);
        o[1][di] = mfma16(ap[1], bv, o[1][di]);
      }
    }
  }

  // epilogue: reduce per-lane lsum across the quad, normalize, write out
  #pragma unroll
  for (int mi = 0; mi < 2; ++mi) {
    #pragma unroll
    for (int r = 0; r < 4; ++r) {
      float l = lsum[mi][r];
      l += __shfl_xor(l, 1);
      l += __shfl_xor(l, 2);
      l += __shfl_xor(l, 4);
      l += __shfl_xor(l, 8);
      float inv = 1.0f / l;
      int lrow = qt * 128 + w * 32 + mi * 16 + qd * 4 + r;
      size_t orow = ((size_t)b * L_ + lrow) * DIM_ + (size_t)h * HD_;
      #pragma unroll
      for (int di = 0; di < 8; ++di)
        Ao[orow + di * 16 + ln] = f2bf(o[mi][di][r] * inv);
    }
  }
}

// ---------------------------------------------------------------------------
extern "C" void kernel_launch(void* const* d_in, const int* in_sizes, int n_in,
                              void* d_out, int out_size, void* d_ws, size_t ws_size,
                              hipStream_t stream) {
  const float* x    = (const float*)d_in[0];
  const float* cs   = (const float*)d_in[1];
  const float* sn   = (const float*)d_in[2];
  const float* wqkv = (const float*)d_in[3];
  const float* wout = (const float*)d_in[4];
  const float* bias = (const float*)d_in[5];
  u16* ws = (u16*)d_ws;

  // Workspace (u16 elems), 92.3 MB total with two time-multiplexed overlaps:
  //   wqkvT 12,582,912  (N=6144 x K=2048 bf16; REUSED for woutT after gemm1)
  //   xbfAo  8,388,608  (x_bf during gemm1; Ao after attn)
  //   Qb/Kbuf/Vbuf 3 x 8,388,608
  u16* wqkvT = ws;
  u16* woutT = ws;                        // same region, written after gemm1
  u16* xbfAo = wqkvT + 12582912;
  u16* Qb    = xbfAo + 8388608;
  u16* Kbuf  = Qb + 8388608;
  u16* Vbuf  = Kbuf + 8388608;

  cvt_bf16<<<dim3(8192), 256, 0, stream>>>(x, xbfAo);
  transpose_cvt<<<dim3(96, 32), 256, 0, stream>>>(wqkv, wqkvT, 2048, 6144);
  gemm_bt<1><<<dim3(48, 32), 256, 0, stream>>>(
      xbfAo, wqkvT, Qb, Kbuf, Vbuf, nullptr, nullptr, M_, NQKV_, DIM_);
  transpose_cvt<<<dim3(32, 32), 256, 0, stream>>>(wout, woutT, 2048, 2048);
  rotary_k<<<dim3(8192), 256, 0, stream>>>(Qb, Kbuf, cs, sn);
  attn_k<<<dim3(512), 256, 0, stream>>>(Qb, Kbuf, Vbuf, xbfAo);
  gemm_bt<2><<<dim3(16, 32), 256, 0, stream>>>(
      xbfAo, woutT, nullptr, nullptr, nullptr, bias, (float*)d_out, M_, DIM_, DIM_);
}

// Round 12
// 466.350 us; speedup vs baseline: 1.0657x; 1.0589x over previous
//
#include <hip/hip_runtime.h>
#include <cstdint>
#include <cstddef>

typedef unsigned short u16;
typedef __attribute__((ext_vector_type(2))) unsigned short u16x2;
typedef __attribute__((ext_vector_type(4))) unsigned short u16x4;
typedef __attribute__((ext_vector_type(8))) unsigned short u16x8;
typedef __attribute__((ext_vector_type(4))) float f32x4;
typedef __attribute__((ext_vector_type(8))) __bf16 bf16x8;

#define B_    2
#define L_    2048
#define DIM_  2048
#define H_    16
#define HD_   128
#define NQKV_ 6144
#define M_    4096   // B_*L_

__device__ __forceinline__ float b2f(u16 h) {
  union { unsigned u; float f; } v; v.u = ((unsigned)h) << 16; return v.f;
}
__device__ __forceinline__ u16 f2bf(float f) {
  unsigned u = __float_as_uint(f);
  u += 0x7fffu + ((u >> 16) & 1u);   // RNE
  return (u16)(u >> 16);
}
__device__ __forceinline__ f32x4 mfma16(bf16x8 a, bf16x8 b, f32x4 c) {
  return __builtin_amdgcn_mfma_f32_16x16x32_bf16(a, b, c, 0, 0, 0);
}
__device__ __forceinline__ void async16(const void* g, void* l) {
  __builtin_amdgcn_global_load_lds(
      (const __attribute__((address_space(1))) unsigned*)g,
      (__attribute__((address_space(3))) unsigned*)l, 16, 0, 0);
}

// ---------------------------------------------------------------------------
// Pre-pass 1: straight f32 -> bf16 convert (x). 4 elems/thread.
// ---------------------------------------------------------------------------
__global__ __launch_bounds__(256) void cvt_bf16(
    const float* __restrict__ src, u16* __restrict__ dst) {
  int i = (blockIdx.x * 256 + threadIdx.x) * 4;
  f32x4 v = *(const f32x4*)&src[i];
  u16x4 o;
  #pragma unroll
  for (int j = 0; j < 4; ++j) o[j] = f2bf(v[j]);
  *(u16x4*)&dst[i] = o;
}

// ---------------------------------------------------------------------------
// Pre-pass 2: f32 (R x C) -> bf16 transposed (C x R). 64x64 LDS tile.
// ---------------------------------------------------------------------------
__global__ __launch_bounds__(256) void transpose_cvt(
    const float* __restrict__ src, u16* __restrict__ dst, int R, int C) {
  __shared__ u16 tile[64][66];
  int r0 = blockIdx.y * 64, c0 = blockIdx.x * 64;
  #pragma unroll
  for (int i = 0; i < 16; ++i) {
    int f = i * 256 + threadIdx.x;
    int r = f >> 6, c = f & 63;
    tile[r][c] = f2bf(src[(size_t)(r0 + r) * C + (c0 + c)]);
  }
  __syncthreads();
  #pragma unroll
  for (int i = 0; i < 8; ++i) {
    int f = i * 256 + threadIdx.x;
    int cr = f >> 5, rp = (f & 31) * 2;
    u16x2 v = {tile[rp][cr], tile[rp + 1][cr]};
    *(u16x2*)&dst[(size_t)(c0 + cr) * R + (r0 + rp)] = v;
  }
}

// ---------------------------------------------------------------------------
// m97-style GEMM, BK=64: C[M,N] = A[M,K] * Bt[N,K]^T, all-bf16, pure
// async16 staging. 128x128 tile, 256 thr. BK=64 halves the per-K-element
// barrier count vs BK=32 (the m97 structure's ~20% vmcnt(0)+barrier drain);
// LDS stays 32 KB (m132's BK=128 regression was the 64 KB occupancy hit).
// Row stride is now 128 B (the 32-way-conflict case), so tiles are
// XOR-SWIZZLED exactly like attn's K-tile (proven): LDS elem =
// row*64 + (col ^ ((row&7)<<3)), realized via inverse-swizzled GLOBAL
// source (involution on elem bits 3..5; 16 B chunks preserved) because
// global_load_lds writes LDS linearly (rule #21). Post-swizzle ds_read
// bank group = (kk*4+qd) ^ (ln&7) -> 8 lanes/group = b128 minimum.
// MODE 1: scatter epilogue into Q/K/V (B*H,L,D) bf16 buffers; t/h/b
//         block-uniform -> hoisted [round 8: ~15 us]. Q/K in interleaved-
//         pair d-layout (2d=x1, 2d+1=x2) for vectorized rotary.
// MODE 2: bias(f32)-add epilogue, f32 row-major store.
// ---------------------------------------------------------------------------
template <int MODE>
__global__ __launch_bounds__(256) void gemm_bt(
    const u16* __restrict__ A, const u16* __restrict__ Bt,
    u16* __restrict__ D0, u16* __restrict__ D1, u16* __restrict__ D2,
    const float* __restrict__ bias, float* __restrict__ outp,
    int M, int N, int K) {
  __shared__ __align__(16) u16 Alds[128 * 64];
  __shared__ __align__(16) u16 Blds[128 * 64];
  const int tid = threadIdx.x;
  const int wave = tid >> 6;
  const int wm = wave >> 1, wn = wave & 1;
  const int ln = tid & 15, qd = (tid >> 4) & 3;
  const int m0 = blockIdx.y * 128, n0 = blockIdx.x * 128;

  f32x4 acc[4][4];
  #pragma unroll
  for (int i = 0; i < 4; ++i)
    #pragma unroll
    for (int j = 0; j < 4; ++j) acc[i][j] = (f32x4){0.f, 0.f, 0.f, 0.f};

  for (int k0 = 0; k0 < K; k0 += 64) {
    __syncthreads();                     // prev iter's fragment ds_reads done
    #pragma unroll
    for (int j = 0; j < 4; ++j) {
      int oe = j * 2048 + tid * 8;       // linear LDS elem offset (128x64)
      int se = oe ^ (((oe >> 6) & 7) << 3);  // swizzled source elem
      int r = oe >> 6, c = se & 63;
      async16(&A[(size_t)(m0 + r) * K + (k0 + c)], &Alds[j * 2048 + wave * 512]);
      async16(&Bt[(size_t)(n0 + r) * K + (k0 + c)], &Blds[j * 2048 + wave * 512]);
    }
    __syncthreads();                     // drains vmcnt before use
    #pragma unroll
    for (int kk = 0; kk < 2; ++kk) {     // two 32-wide K-slices
      bf16x8 af[4], bfr[4];
      #pragma unroll
      for (int mi = 0; mi < 4; ++mi) {
        int arow = wm * 64 + mi * 16 + ln;
        af[mi] = *(const bf16x8*)&Alds[arow * 64 +
                     ((kk * 32 + qd * 8) ^ ((arow & 7) << 3))];
      }
      #pragma unroll
      for (int ni = 0; ni < 4; ++ni) {
        int brow = wn * 64 + ni * 16 + ln;
        bfr[ni] = *(const bf16x8*)&Blds[brow * 64 +
                     ((kk * 32 + qd * 8) ^ ((brow & 7) << 3))];
      }
      #pragma unroll
      for (int mi = 0; mi < 4; ++mi)
        #pragma unroll
        for (int ni = 0; ni < 4; ++ni)
          acc[mi][ni] = mfma16(af[mi], bfr[ni], acc[mi][ni]);
    }
  }

  // epilogue: C/D layout col=lane&15, row=quad*4+reg  [m89-verified]
  if (MODE == 2) {
    #pragma unroll
    for (int mi = 0; mi < 4; ++mi)
      #pragma unroll
      for (int ni = 0; ni < 4; ++ni)
        #pragma unroll
        for (int r = 0; r < 4; ++r) {
          int row = m0 + wm * 64 + mi * 16 + qd * 4 + r;
          int col = n0 + wn * 64 + ni * 16 + ln;
          outp[(size_t)row * N + col] = acc[mi][ni][r] + bias[col];
        }
  } else {
    const int t  = n0 >> 11;             // 0=q, 1=k, 2=v   (block-uniform)
    const int hh = (n0 & 2047) >> 7;     // head            (block-uniform)
    const int bb = m0 >> 11;             // batch           (block-uniform)
    const int l0 = (m0 & 2047) + wm * 64;
    // Q/K (t<2): interleaved-pair pos = ((ln+ni*16)<<1)|wn; V natural.
    const int d0    = (t != 2) ? (((ln) << 1) | wn) : (wn * 64 + ln);
    const int dstep = (t != 2) ? 32 : 16;
    u16* dst = (t == 0) ? D0 : ((t == 1) ? D1 : D2);
    u16* basep = dst + ((size_t)(bb * H_ + hh) * L_) * HD_;
    #pragma unroll
    for (int mi = 0; mi < 4; ++mi)
      #pragma unroll
      for (int r = 0; r < 4; ++r) {
        int l = l0 + mi * 16 + qd * 4 + r;
        #pragma unroll
        for (int ni = 0; ni < 4; ++ni)
          basep[(size_t)l * HD_ + d0 + ni * dstep] = f2bf(acc[mi][ni][r]);
      }
  }
}

// ---------------------------------------------------------------------------
// In-place rotary on Q and K in INTERLEAVED-PAIR layout (B*H, L, 128):
// position 2d = x1(d), 2d+1 = x2(d). Fully vectorized: each thread does
// 4 pairs = one u16x8 (16 B) load + f32x4 cos + f32x4 sin + one 16 B store.
// ---------------------------------------------------------------------------
__global__ __launch_bounds__(256) void rotary_k(
    u16* __restrict__ Q, u16* __restrict__ Kb,
    const float* __restrict__ cs, const float* __restrict__ sn) {
  const int tid = threadIdx.x;
  const int tensor = tid >> 7;            // 0 = Q, 1 = K
  const int rsub = (tid >> 4) & 7;        // row within block's 8
  const int j = tid & 15;                 // 16 threads per row
  const int row = blockIdx.x * 8 + rsub;  // flat (bh*L + l)
  const int l = row & (L_ - 1);
  u16* P = tensor ? Kb : Q;
  size_t base = (size_t)row * HD_ + j * 8;
  u16x8 v = *(const u16x8*)&P[base];
  f32x4 c = *(const f32x4*)&cs[l * 64 + j * 4];
  f32x4 s = *(const f32x4*)&sn[l * 64 + j * 4];
  u16x8 o;
  #pragma unroll
  for (int e = 0; e < 4; ++e) {
    float x1 = b2f(v[2 * e]), x2 = b2f(v[2 * e + 1]);
    o[2 * e]     = f2bf(x1 * c[e] - x2 * s[e]);
    o[2 * e + 1] = f2bf(x2 * c[e] + x1 * s[e]);
  }
  *(u16x8*)&P[base] = o;
}

// ---------------------------------------------------------------------------
// Flash attention. grid (16 qtiles, 32 bh), 256 thr (4 waves).
// Q,K,V all (B*H, L, 128) bf16. BM=128, BN=64 keys/iter.
//
// ROUND-10 EXACT (measured 169 us, 116 VGPR, 21% occupancy). Round-11's
// XCD remap cut FETCH 139->25 MB but COST 11 us (L2 hotspot; fetch latency
// was already occupancy-hidden) -> reverted. attn is latency/VALU-bound;
// memory is ruled out by that experiment.
//
// Session rules (rounds 4-8):
//  - VGPR <= 128 or occupancy halves (64-granular quantum).
//  - NO sched_barrier/inline-asm fences here (pin live ranges, +24 VGPR).
//  - NO defer-max branch (+24 VGPR).
//  - Occupancy (3 blocks/CU) is the latency hider.
//
// LDS swizzles (both-sides, rule #21):
//   K/Q tiles: elem = row*128 + (col ^ ((row&7)<<3)); staged via inverse-
//     swizzled GLOBAL source (global_load_lds writes LDS linearly).
//   Vlds [128][64]: elem = row*64 + (col ^ (((row>>1)&7)<<3)).
//   Plds stride-72. LDS = 50 KB -> 3 blocks/CU.
// Deferred l-reduce: lsum kept PER-LANE, quad-reduced once in epilogue.
// ---------------------------------------------------------------------------
__global__ __launch_bounds__(256, 4) void attn_k(
    const u16* __restrict__ Q, const u16* __restrict__ Kb,
    const u16* __restrict__ V, u16* __restrict__ Ao) {
  __shared__ __align__(16) u16 lds[25600];     // 50 KB
  u16* Klds = lds;               // [64 keys][128 d]  (swizzled)
  u16* Vlds = lds + 8192;        // [128 d][64 keys]  (swizzled)
  u16* Plds = lds + 16384;       // [128 q][72], keys 0..63 used
  const int tid = threadIdx.x;
  const int w = tid >> 6, lane = tid & 63;
  const int ln = lane & 15, qd = lane >> 4;
  const int qt = blockIdx.x, bh = blockIdx.y;
  const int b = bh >> 4, h = bh & 15;
  const size_t slab = (size_t)bh * (L_ * HD_);
  const int vd0 = 2 * lane;                    // V staging: d-pair

  // stage Q tile (contiguous 32 KB, overlays K+V) via async16, pre-swizzled
  #pragma unroll
  for (int j = 0; j < 8; ++j) {
    int oe = j * 2048 + w * 512 + lane * 8;        // linear LDS elem offset
    int se = oe ^ (((oe >> 7) & 7) << 3);          // swizzled global source
    async16(&Q[slab + (size_t)qt * 16384 + se], &lds[j * 2048 + w * 512]);
  }
  __syncthreads();
  bf16x8 aq[2][4];                         // Q fragments in registers
  #pragma unroll
  for (int mi = 0; mi < 2; ++mi) {
    int qrow = w * 32 + mi * 16 + ln;
    #pragma unroll
    for (int kc = 0; kc < 4; ++kc)
      aq[mi][kc] = *(const bf16x8*)&lds[qrow * 128 +
                                        ((kc * 32 + qd * 8) ^ ((qrow & 7) << 3))];
  }

  f32x4 o[2][8];
  #pragma unroll
  for (int i = 0; i < 2; ++i)
    #pragma unroll
    for (int j = 0; j < 8; ++j) o[i][j] = (f32x4){0.f, 0.f, 0.f, 0.f};
  float mst[2][4], lsum[2][4];             // lsum = PER-LANE partial sum
  #pragma unroll
  for (int i = 0; i < 2; ++i)
    #pragma unroll
    for (int r = 0; r < 4; ++r) { mst[i][r] = -1e30f; lsum[i][r] = 0.f; }
  const float SC = 0.12751744f;            // (1/sqrt(128)) * log2(e)

  for (int it = 0; it < 32; ++it) {
    // V global loads -> regs (no LDS touch; before barrier for latency)
    unsigned vv[2][8];
    #pragma unroll
    for (int n2 = 0; n2 < 2; ++n2) {
      int key0 = (w + n2 * 4) * 8;
      #pragma unroll
      for (int e = 0; e < 8; ++e)
        vv[n2][e] = *(const unsigned*)&V[slab + (size_t)(it * 64 + key0 + e) * 128 + vd0];
    }
    __syncthreads();                       // B1: prev iter's LDS readers done
    // K tile via async16, source pre-swizzled (see header comment)
    #pragma unroll
    for (int j = 0; j < 4; ++j) {
      int oe = j * 2048 + w * 512 + lane * 8;
      int se = oe ^ (((oe >> 7) & 7) << 3);
      async16(&Kb[slab + (size_t)it * 8192 + se], &Klds[j * 2048 + w * 512]);
    }
    // V transpose stores (swizzled [128][64]; conflict-free, see header)
    {
      int swz = (lane & 7) << 3;           // ((vd0>>1)&7)<<3, vd0 even
      #pragma unroll
      for (int n2 = 0; n2 < 2; ++n2) {
        int key0 = (w + n2 * 4) * 8;
        u16x8 lo, hi;
        #pragma unroll
        for (int e = 0; e < 8; ++e) {
          lo[e] = (u16)(vv[n2][e] & 0xffffu);
          hi[e] = (u16)(vv[n2][e] >> 16);
        }
        *(u16x8*)&Vlds[vd0 * 64 + (key0 ^ swz)] = lo;
        *(u16x8*)&Vlds[(vd0 + 1) * 64 + (key0 ^ swz)] = hi;
      }
    }
    __syncthreads();                       // B2: drains vmcnt (K) + lgkm (V)

    // S = Q K^T  (raw dot products; scale folded into softmax)
    f32x4 sa[2][4];
    #pragma unroll
    for (int i = 0; i < 2; ++i)
      #pragma unroll
      for (int j = 0; j < 4; ++j) sa[i][j] = (f32x4){0.f, 0.f, 0.f, 0.f};
    #pragma unroll
    for (int kc = 0; kc < 4; ++kc) {
      bf16x8 bk[4];
      #pragma unroll
      for (int ni = 0; ni < 4; ++ni) {
        int krow = ni * 16 + ln;
        bk[ni] = *(const bf16x8*)&Klds[krow * 128 +
                                       ((kc * 32 + qd * 8) ^ ((krow & 7) << 3))];
      }
      #pragma unroll
      for (int mi = 0; mi < 2; ++mi)
        #pragma unroll
        for (int ni = 0; ni < 4; ++ni)
          sa[mi][ni] = mfma16(aq[mi][kc], bk[ni], sa[mi][ni]);
    }

    // online softmax per q-row; row r of tile lives on one quad (16 lanes)
    #pragma unroll
    for (int mi = 0; mi < 2; ++mi) {
      #pragma unroll
      for (int r = 0; r < 4; ++r) {
        float tmax = -1e30f;
        #pragma unroll
        for (int ni = 0; ni < 4; ++ni) tmax = fmaxf(tmax, sa[mi][ni][r]);
        tmax *= SC;
        tmax = fmaxf(tmax, __shfl_xor(tmax, 1));
        tmax = fmaxf(tmax, __shfl_xor(tmax, 2));
        tmax = fmaxf(tmax, __shfl_xor(tmax, 4));
        tmax = fmaxf(tmax, __shfl_xor(tmax, 8));
        float mnew = fmaxf(mst[mi][r], tmax);
        float alpha = exp2f(mst[mi][r] - mnew);
        float p[4], rs = 0.f;
        #pragma unroll
        for (int ni = 0; ni < 4; ++ni) {
          p[ni] = exp2f(sa[mi][ni][r] * SC - mnew);
          rs += p[ni];
        }
        lsum[mi][r] = lsum[mi][r] * alpha + rs;  // per-lane partial
        mst[mi][r] = mnew;
        #pragma unroll
        for (int di = 0; di < 8; ++di) o[mi][di][r] *= alpha;
        #pragma unroll
        for (int ni = 0; ni < 4; ++ni)     // P in A-operand layout [q][key]
          Plds[(w * 32 + mi * 16 + qd * 4 + r) * 72 + ni * 16 + ln] = f2bf(p[ni]);
      }
    }

    __syncthreads();                       // B3: P writes visible

    // O += P V
    #pragma unroll
    for (int kc = 0; kc < 2; ++kc) {
      bf16x8 ap[2];
      #pragma unroll
      for (int mi = 0; mi < 2; ++mi)
        ap[mi] = *(const bf16x8*)&Plds[(w * 32 + mi * 16 + ln) * 72 + kc * 32 + qd * 8];
      #pragma unroll
      for (int di = 0; di < 8; ++di) {
        int vrow = di * 16 + ln;
        bf16x8 bv = *(const bf16x8*)&Vlds[vrow * 64 +
                         ((kc * 32 + qd * 8) ^ (((vrow >> 1) & 7) << 3))];
        o[0][di] = mfma16(ap[0], bv, o[0][di]);
        o[1][di] = mfma16(ap[1], bv, o[1][di]);
      }
    }
  }

  // epilogue: reduce per-lane lsum across the quad, normalize, write out
  #pragma unroll
  for (int mi = 0; mi < 2; ++mi) {
    #pragma unroll
    for (int r = 0; r < 4; ++r) {
      float l = lsum[mi][r];
      l += __shfl_xor(l, 1);
      l += __shfl_xor(l, 2);
      l += __shfl_xor(l, 4);
      l += __shfl_xor(l, 8);
      float inv = 1.0f / l;
      int lrow = qt * 128 + w * 32 + mi * 16 + qd * 4 + r;
      size_t orow = ((size_t)b * L_ + lrow) * DIM_ + (size_t)h * HD_;
      #pragma unroll
      for (int di = 0; di < 8; ++di)
        Ao[orow + di * 16 + ln] = f2bf(o[mi][di][r] * inv);
    }
  }
}

// ---------------------------------------------------------------------------
extern "C" void kernel_launch(void* const* d_in, const int* in_sizes, int n_in,
                              void* d_out, int out_size, void* d_ws, size_t ws_size,
                              hipStream_t stream) {
  const float* x    = (const float*)d_in[0];
  const float* cs   = (const float*)d_in[1];
  const float* sn   = (const float*)d_in[2];
  const float* wqkv = (const float*)d_in[3];
  const float* wout = (const float*)d_in[4];
  const float* bias = (const float*)d_in[5];
  u16* ws = (u16*)d_ws;

  // Workspace (u16 elems), 92.3 MB total with two time-multiplexed overlaps:
  //   wqkvT 12,582,912  (N=6144 x K=2048 bf16; REUSED for woutT after gemm1)
  //   xbfAo  8,388,608  (x_bf during gemm1; Ao after attn)
  //   Qb/Kbuf/Vbuf 3 x 8,388,608
  u16* wqkvT = ws;
  u16* woutT = ws;                        // same region, written after gemm1
  u16* xbfAo = wqkvT + 12582912;
  u16* Qb    = xbfAo + 8388608;
  u16* Kbuf  = Qb + 8388608;
  u16* Vbuf  = Kbuf + 8388608;

  cvt_bf16<<<dim3(8192), 256, 0, stream>>>(x, xbfAo);
  transpose_cvt<<<dim3(96, 32), 256, 0, stream>>>(wqkv, wqkvT, 2048, 6144);
  gemm_bt<1><<<dim3(48, 32), 256, 0, stream>>>(
      xbfAo, wqkvT, Qb, Kbuf, Vbuf, nullptr, nullptr, M_, NQKV_, DIM_);
  transpose_cvt<<<dim3(32, 32), 256, 0, stream>>>(wout, woutT, 2048, 2048);
  rotary_k<<<dim3(8192), 256, 0, stream>>>(Qb, Kbuf, cs, sn);
  attn_k<<<dim3(16, 32), 256, 0, stream>>>(Qb, Kbuf, Vbuf, xbfAo);
  gemm_bt<2><<<dim3(16, 32), 256, 0, stream>>>(
      xbfAo, woutT, nullptr, nullptr, nullptr, bias, (float*)d_out, M_, DIM_, DIM_);
}